// Round 15
// baseline (851.491 us; speedup 1.0000x reference)
//
#include <hip/hip_runtime.h>
#include <hip/hip_bf16.h>

typedef unsigned short u16;
typedef unsigned int u32;
typedef __attribute__((ext_vector_type(8))) short short8;
typedef __attribute__((ext_vector_type(4))) float f32x4;

constexpr int SA     = 160;    // act row stride (bf16): 320 B
constexpr int BLK_E  = 128;    // 4 waves x 32 edges, all waves independent
constexpr int NTHR   = 256;
constexpr int CHUNK  = 512;    // u16 elems per (ks,j) fragment chunk = 1 KB
constexpr int WSLOT  = 50 * CHUNK;              // elems per layer (5 ks x 10 j)
constexpr size_t WS_HDR   = 262144;             // weights header

// slice schedule: s=0 -> (L0,ks0); s=1..15 -> L1..L3 (5 ks each); s=16..20 -> L4
constexpr int Ls (int s) { return s == 0 ? 0 : (s <= 15 ? 1 + (s - 1) / 5 : 4); }
constexpr int Kss(int s) { return s == 0 ? 0 : (s <= 15 ? (s - 1) % 5 : s - 16); }

__device__ __forceinline__ u16 f2bf(float f) {  // RNE (prep only)
    union { float f; unsigned u; } c; c.f = f;
    return (u16)((c.u + 0x7fffu + ((c.u >> 16) & 1u)) >> 16);
}
__device__ __forceinline__ unsigned pk_bf16(float a, float b) {  // v_cvt_pk_bf16_f32
    float2 f; f.x = a; f.y = b;
    __hip_bfloat162 h = __float22bfloat162_rn(f);
    return *(unsigned*)&h;
}

// act k'-storage permutation (tiles 0-3 / 4 / 5-8 / 9)
__device__ __forceinline__ int kperm(int kp) {
    if (kp < 64)  return (kp & 3) * 16 + (kp >> 2);
    if (kp < 128) { const int m = kp - 64; return (5 + (m & 3)) * 16 + (m >> 2); }
    if (kp < 144) return 4 * 16 + (kp - 128);
    if (kp < 160) return 9 * 16 + (kp - 144);
    return 1 << 30;
}

// ---- prep: weights -> fragment chunks + BOTH zero-fills (fused memsets) ----
// blockIdx.y: 0-4 weights, 5 cursor zero, 6 Ep zero (float4).
__global__ void prep_all(const float* __restrict__ W0, const float* __restrict__ W1,
                         const float* __restrict__ W2, const float* __restrict__ W3,
                         const float* __restrict__ W4,
                         const float* __restrict__ B0, const float* __restrict__ B1,
                         const float* __restrict__ B2, const float* __restrict__ B3,
                         const float* __restrict__ B4,
                         u16* __restrict__ Wt, u32* __restrict__ cursor, int n_nodes,
                         float* __restrict__ Ep, int ep_quads)
{
    const int l = blockIdx.y;
    const int tid0 = blockIdx.x * blockDim.x + threadIdx.x;
    const int stride = gridDim.x * blockDim.x;
    if (l == 5) {
        for (int idx = tid0; idx < n_nodes; idx += stride) cursor[idx] = 0u;
        return;
    }
    if (l == 6) {
        float4* p = (float4*)Ep;
        const float4 z4 = {0.f, 0.f, 0.f, 0.f};
        for (int idx = tid0; idx < ep_quads; idx += stride) p[idx] = z4;
        return;
    }
    const float* W; const float* B; int DI, DO; bool perm;
    if      (l == 0) { W = W0; B = B0; DI = 13;  DO = 150; perm = false; }
    else if (l == 1) { W = W1; B = B1; DI = 150; DO = 150; perm = true;  }
    else if (l == 2) { W = W2; B = B2; DI = 150; DO = 150; perm = true;  }
    else if (l == 3) { W = W3; B = B3; DI = 150; DO = 150; perm = true;  }
    else             { W = W4; B = B4; DI = 150; DO = 50;  perm = true;  }
    const int kbias = (l == 0) ? 13 : 150;      // constant-1 input row
    u16* dst = Wt + (size_t)l * WSLOT;
    for (int idx = tid0; idx < WSLOT; idx += stride) {
        const int chunk = idx / CHUNK;            // = ks*10 + j
        const int within = idx - chunk * CHUNK;
        const int lane = within >> 3, e = within & 7;
        const int ks = chunk / 10, j = chunk - ks * 10;
        const int c = lane & 15, q = lane >> 4;
        const int n = j * 16 + c;
        const int kphys = ks * 32 + q * 8 + e;
        const int klog = perm ? kperm(kphys) : kphys;
        float v = 0.f;
        if (n < DO) {
            if (klog < DI)          v = W[klog * DO + n];
            else if (klog == kbias) v = B[n];     // folded bias row
        }
        dst[idx] = f2bf(v);
    }
}

// ---- B half-slice load by half-index h (0..36) -> registers ----------------
__device__ __forceinline__ void loadHalfH(const u16* __restrict__ Wt, int h,
                                          int lane, short8* buf)
{
    int l, ks, g, nch;
    if (h < 32) { const int s = h >> 1; l = Ls(s); ks = Kss(s); g = h & 1; nch = 5; }
    else        { l = 4; ks = h - 32; g = 0; nch = 4; }
    const u16* base = Wt + (size_t)l * WSLOT + (size_t)(ks * 10 + g * 5) * CHUNK
                         + lane * 8;
#pragma unroll
    for (int jj = 0; jj < 5; ++jj)
        if (jj < nch) buf[jj] = *(const short8*)&base[jj * CHUNK];
}

// ---- full-width epilogue: relu + packed bf16, k'-permuted store ------------
__device__ __forceinline__ void epilogueF(u16* act, int ebase, int col, int quad,
                                          f32x4 (&acc)[2][10])
{
#pragma unroll
    for (int mtl = 0; mtl < 2; ++mtl)
#pragma unroll
        for (int r = 0; r < 4; ++r) {
            const int row = ebase + mtl * 16 + quad * 4 + r;
            u16* rp = &act[row * SA];
            uint2 p0, p1;
            p0.x = pk_bf16(fmaxf(acc[mtl][0][r], 0.f), fmaxf(acc[mtl][1][r], 0.f));
            p0.y = pk_bf16(fmaxf(acc[mtl][2][r], 0.f), fmaxf(acc[mtl][3][r], 0.f));
            p1.x = pk_bf16(fmaxf(acc[mtl][5][r], 0.f), fmaxf(acc[mtl][6][r], 0.f));
            p1.y = pk_bf16(fmaxf(acc[mtl][7][r], 0.f), fmaxf(acc[mtl][8][r], 0.f));
            *(uint2*)&rp[col * 4]      = p0;               // tiles 0-3
            *(uint2*)&rp[64 + col * 4] = p1;               // tiles 5-8
            rp[128 + col] = (u16)pk_bf16(fmaxf(acc[mtl][4][r], 0.f), 0.f); // tile 4
            u16 sv = (u16)pk_bf16(fmaxf(acc[mtl][9][r], 0.f), 0.f);
            if (col == 6) sv = 0x3F80;                     // n=150 := 1.0 (bias)
            rp[144 + col] = sv;                            // tile 9
        }
}

// ====================== counting sort of edges by tgt =======================
__global__ void hist_kernel(const int* __restrict__ tgt, u32* __restrict__ cnt,
                            int n_edges)
{
    const int stride = gridDim.x * blockDim.x;
    for (int e = blockIdx.x * blockDim.x + threadIdx.x; e < n_edges; e += stride)
        atomicAdd(&cnt[tgt[e]], 1u);
}

__global__ void scan1_kernel(const u32* __restrict__ cnt, u32* __restrict__ offs,
                             u32* __restrict__ bsum, int n)
{
    __shared__ u32 s[256];
    const int i = blockIdx.x * 256 + threadIdx.x;
    const u32 v = (i < n) ? cnt[i] : 0u;
    s[threadIdx.x] = v; __syncthreads();
#pragma unroll
    for (int d = 1; d < 256; d <<= 1) {
        const u32 t = (threadIdx.x >= d) ? s[threadIdx.x - d] : 0u;
        __syncthreads();
        s[threadIdx.x] += t;
        __syncthreads();
    }
    if (i < n) offs[i] = s[threadIdx.x] - v;         // exclusive within block
    if (threadIdx.x == 255) bsum[blockIdx.x] = s[255];   // RAW block total
}

// scan3 absorbs scan2: each block sums bsum[0..blockIdx) itself.
__global__ void scan3_kernel(const u32* __restrict__ offs, const u32* __restrict__ bsum,
                             u32* __restrict__ cursor, int n)
{
    __shared__ u32 s[256];
    u32 part = 0;
    for (int j = threadIdx.x; j < blockIdx.x; j += 256) part += bsum[j];
    s[threadIdx.x] = part;
    __syncthreads();
#pragma unroll
    for (int d = 128; d > 0; d >>= 1) {
        if (threadIdx.x < d) s[threadIdx.x] += s[threadIdx.x + d];
        __syncthreads();
    }
    const u32 base = s[0];
    const int i = blockIdx.x * 256 + threadIdx.x;
    if (i < n) cursor[i] = offs[i] + base;
}

// perm: single int2 scatter per edge (the PROVEN gather format)
__global__ void perm_kernel(const int* __restrict__ src, const int* __restrict__ tgt,
                            u32* __restrict__ cursor, int2* __restrict__ sg,
                            int n_edges)
{
    const int stride = gridDim.x * blockDim.x;
    for (int e = blockIdx.x * blockDim.x + threadIdx.x; e < n_edges; e += stride) {
        const int g = tgt[e];
        const u32 pos = atomicAdd(&cursor[g], 1u);
        sg[pos] = make_int2(src[e], g);
    }
}

// ------------------------------- Edge kernel --------------------------------
// BARRIER-FREE, wave-owns-32-edges + XCD swizzle + T5 setprio (R14: -10%).
// R15: setprio window opens BEFORE the A-frag ds_reads (covers the
// ds_read -> lgkm -> MFMA feed path); low-prio only during B-prefetch issue.
__global__ __launch_bounds__(NTHR, 3) void edge_kernel(
    const float* __restrict__ t, const float* __restrict__ x, const float* __restrict__ Ofx,
    const int2* __restrict__ sgp,
    const u16* __restrict__ Wt,
    float* __restrict__ Ep, int n_edges)
{
    __shared__ __align__(16) u16 act[BLK_E * SA];      // 40960 B exactly

    // bijective XCD-chunk swizzle (m204)
    const int nwg  = gridDim.x;
    const int orig = blockIdx.x;
    const int xcd  = orig & 7;
    const int q = nwg >> 3, r = nwg & 7;
    const int bid = (xcd < r ? xcd * (q + 1) : r * (q + 1) + (xcd - r) * q)
                    + (orig >> 3);

    const int tid   = threadIdx.x;
    const int lane  = tid & 63;
    const int wv    = tid >> 6;        // 0..3
    const int ebase = wv * 32;         // this wave's 32 act rows
    const int col   = lane & 15;
    const int quad  = lane >> 4;

    // ---- gather R': this wave's 32 edges (lanes 0-31, one edge each) -------
    int gval = -1;                     // tgt of this lane's edge (lanes 0-31)
    if (lane < 32) {
        const int e = ebase + lane;
        const long long ge = (long long)bid * BLK_E + e;
        const bool valid = ge < n_edges;
        const int2 sg = valid ? sgp[ge] : make_int2(0, 0);
        gval = valid ? sg.y : -1;
        const float4 xs = valid ? *(const float4*)&x[(size_t)sg.x * 4] : float4{0, 0, 0, 0};
        const float2 os = valid ? *(const float2*)&Ofx[(size_t)sg.x * 2] : float2{0, 0};
        const float4 xg = valid ? *(const float4*)&x[(size_t)sg.y * 4] : float4{0, 0, 0, 0};
        const float2 og = valid ? *(const float2*)&Ofx[(size_t)sg.y * 2] : float2{0, 0};
        const float tv = valid ? t[0] : 0.f;
        uint4 w0, w1;
        w0.x = pk_bf16(xs.x, xs.y); w0.y = pk_bf16(xs.z, xs.w);
        w0.z = pk_bf16(os.x, os.y); w0.w = pk_bf16(xg.x, xg.y);
        w1.x = pk_bf16(xg.z, xg.w); w1.y = pk_bf16(og.x, og.y);
        w1.z = pk_bf16(tv, 1.0f);   w1.w = 0u;     // k=13 := 1 (bias neuron)
        u16* rp = &act[e * SA];
        *(uint4*)&rp[0]  = w0;
        *(uint4*)&rp[8]  = w1;
        *(uint4*)&rp[16] = uint4{0, 0, 0, 0};
        *(uint4*)&rp[24] = uint4{0, 0, 0, 0};
    }
    // no __syncthreads: same-wave DS ordering; rows are wave-private.

    const f32x4 z = {0.f, 0.f, 0.f, 0.f};
    f32x4 acc[2][10];
    short8 Wb[2][5];
    short8 Af[2];

    // prologue: prefetch halves 0 (->Wb[0]) and 1 (->Wb[1])
    loadHalfH(Wt, 0, lane, Wb[0]);
    loadHalfH(Wt, 1, lane, Wb[1]);

    // ---- s=0..15: L0..L3, full N width per wave ----------------------------
#pragma unroll
    for (int s = 0; s <= 15; ++s) {
        const int ks = Kss(s);
        const bool first = (s == 0) || (ks == 0);
        __builtin_amdgcn_s_setprio(1);                    // open BEFORE A-reads
#pragma unroll
        for (int mtl = 0; mtl < 2; ++mtl)
            Af[mtl] = *(const short8*)&act[(ebase + mtl * 16 + col) * SA
                                           + ks * 32 + quad * 8];
#pragma unroll
        for (int jj = 0; jj < 5; ++jj)
#pragma unroll
            for (int mtl = 0; mtl < 2; ++mtl)
                acc[mtl][jj] = __builtin_amdgcn_mfma_f32_16x16x32_bf16(
                    Af[mtl], Wb[0][jj], first ? z : acc[mtl][jj], 0, 0, 0);
        __builtin_amdgcn_s_setprio(0);                    // low during B-prefetch
        loadHalfH(Wt, 2 * s + 2, lane, Wb[0]);            // <= 32
        __builtin_amdgcn_s_setprio(1);
#pragma unroll
        for (int jj = 0; jj < 5; ++jj)
#pragma unroll
            for (int mtl = 0; mtl < 2; ++mtl)
                acc[mtl][5 + jj] = __builtin_amdgcn_mfma_f32_16x16x32_bf16(
                    Af[mtl], Wb[1][jj], first ? z : acc[mtl][5 + jj], 0, 0, 0);
        __builtin_amdgcn_s_setprio(0);
        loadHalfH(Wt, 2 * s + 3, lane, Wb[1]);            // <= 33
        if (s == 0 || ks == 4)
            epilogueF(act, ebase, col, quad, acc);
    }

    // ---- L4: ks=0..4, N=50 (4 tiles), both M-tiles -------------------------
    f32x4 acc4[2][4];
#pragma unroll
    for (int ks4 = 0; ks4 < 5; ++ks4) {
        const int h = 32 + ks4;
        __builtin_amdgcn_s_setprio(1);                    // open BEFORE A-reads
#pragma unroll
        for (int mtl = 0; mtl < 2; ++mtl)
            Af[mtl] = *(const short8*)&act[(ebase + mtl * 16 + col) * SA
                                           + ks4 * 32 + quad * 8];
#pragma unroll
        for (int jj = 0; jj < 4; ++jj)
#pragma unroll
            for (int mtl = 0; mtl < 2; ++mtl)
                acc4[mtl][jj] = __builtin_amdgcn_mfma_f32_16x16x32_bf16(
                    Af[mtl], Wb[h & 1][jj], (ks4 == 0) ? z : acc4[mtl][jj], 0, 0, 0);
        __builtin_amdgcn_s_setprio(0);
        if (h + 2 <= 36) loadHalfH(Wt, h + 2, lane, Wb[h & 1]);
    }

    // ---- wave-private E tile + run-scan scatter ----------------------------
    float* actF = (float*)&act[ebase * SA];   // f32 [32][52] on own rows
#pragma unroll
    for (int mtl = 0; mtl < 2; ++mtl)
#pragma unroll
        for (int jj = 0; jj < 4; ++jj) {
            const int n = jj * 16 + col;
            if (n < 50) {
#pragma unroll
                for (int r = 0; r < 4; ++r)
                    actF[(mtl * 16 + quad * 4 + r) * 52 + n] = acc4[mtl][jj][r];
            }
        }
    if (lane < 50) {
        const int c = lane;
        int   cur = __shfl(gval, 0);
        float a   = 0.f;
#pragma unroll
        for (int rb = 0; rb < 4; ++rb) {
            float vb[8];
#pragma unroll
            for (int j = 0; j < 8; ++j)
                vb[j] = actF[(rb * 8 + j) * 52 + c];
#pragma unroll
            for (int j = 0; j < 8; ++j) {
                const int g = __shfl(gval, rb * 8 + j);
                if (g != cur) {
                    if (cur >= 0) atomicAdd(&Ep[(size_t)cur * 50 + c], a);
                    a = 0.f; cur = g;
                }
                a += vb[j];
            }
        }
        if (cur >= 0) atomicAdd(&Ep[(size_t)cur * 50 + c], a);
    }
}

// ---------------- Node kernel: fO MLP (fp32 VALU) ---------------------------
template<int DI, int DO, bool RELU>
__device__ __forceinline__ void mlp_layer_t(
    const float* __restrict__ W, const float* __restrict__ B,
    float (*in)[64], float (*out)[64], int tid)
{
    const int et = tid & 15;
    const int jt = tid >> 4;
    constexpr int NG = (DO + 15) / 16;

    float acc0[NG], acc1[NG], acc2[NG], acc3[NG];
#pragma unroll
    for (int g = 0; g < NG; ++g) {
        const int j = jt + 16 * g;
        const float bb = (j < DO) ? B[j] : 0.f;
        acc0[g] = bb; acc1[g] = bb; acc2[g] = bb; acc3[g] = bb;
    }
    for (int k = 0; k < DI; ++k) {
        const float4 a = *(const float4*)&in[k][et * 4];
#pragma unroll
        for (int g = 0; g < NG; ++g) {
            const int j = jt + 16 * g;
            const float wv = (j < DO) ? W[k * DO + j] : 0.f;
            acc0[g] = fmaf(a.x, wv, acc0[g]);
            acc1[g] = fmaf(a.y, wv, acc1[g]);
            acc2[g] = fmaf(a.z, wv, acc2[g]);
            acc3[g] = fmaf(a.w, wv, acc3[g]);
        }
    }
#pragma unroll
    for (int g = 0; g < NG; ++g) {
        const int j = jt + 16 * g;
        if (j < DO) {
            float4 v; v.x = acc0[g]; v.y = acc1[g]; v.z = acc2[g]; v.w = acc3[g];
            if (RELU) {
                v.x = fmaxf(v.x, 0.f); v.y = fmaxf(v.y, 0.f);
                v.z = fmaxf(v.z, 0.f); v.w = fmaxf(v.w, 0.f);
            }
            *(float4*)&out[j][et * 4] = v;
        }
    }
}

__global__ __launch_bounds__(256, 3) void node_kernel(
    const float* __restrict__ Ep,
    const float* __restrict__ W0, const float* __restrict__ B0,
    const float* __restrict__ W1, const float* __restrict__ B1,
    float* __restrict__ P, int n_nodes)
{
    __shared__ float bufA[104][64];
    __shared__ float bufB[104][64];
    const int tid = threadIdx.x;
    const int n0  = blockIdx.x * 64;

    for (int idx = tid; idx < 64 * 50; idx += 256) {
        const int e = idx / 50;
        const int k = idx - e * 50;
        const int n = n0 + e;
        bufA[k][e] = (n < n_nodes) ? Ep[(size_t)n * 50 + k] : 0.f;
    }
    __syncthreads();
    mlp_layer_t<50, 100, true >(W0, B0, bufA, bufB, tid); __syncthreads();
    mlp_layer_t<100, 4, false>(W1, B1, bufB, bufA, tid); __syncthreads();
    for (int idx = tid; idx < 64 * 4; idx += 256) {
        const int e = idx & 63;
        const int j = idx >> 6;
        const int n = n0 + e;
        if (n < n_nodes) P[(size_t)n * 4 + j] = bufA[j][e];
    }
}

// ------------------------------- launcher -----------------------------------
extern "C" void kernel_launch(void* const* d_in, const int* in_sizes, int n_in,
                              void* d_out, int out_size, void* d_ws, size_t ws_size,
                              hipStream_t stream)
{
    const float* t   = (const float*)d_in[0];
    const float* x   = (const float*)d_in[1];
    const float* Ofx = (const float*)d_in[2];
    const int*   src = (const int*)d_in[3];
    const int*   tgt = (const int*)d_in[4];
    const float* W0  = (const float*)d_in[5];  const float* B0 = (const float*)d_in[6];
    const float* W1  = (const float*)d_in[7];  const float* B1 = (const float*)d_in[8];
    const float* W2  = (const float*)d_in[9];  const float* B2 = (const float*)d_in[10];
    const float* W3  = (const float*)d_in[11]; const float* B3 = (const float*)d_in[12];
    const float* W4  = (const float*)d_in[13]; const float* B4 = (const float*)d_in[14];
    const float* OW0 = (const float*)d_in[15]; const float* OB0 = (const float*)d_in[16];
    const float* OW1 = (const float*)d_in[17]; const float* OB1 = (const float*)d_in[18];

    const int n_nodes = in_sizes[1] / 4;
    const int n_edges = in_sizes[3];

    // workspace layout (all 256-B aligned)
    auto align256 = [](size_t v) { return (v + 255) & ~(size_t)255; };
    char* ws = (char*)d_ws;
    const size_t copy_elems = (size_t)n_nodes * 50;
    size_t o = 0;
    u16*   Wt       = (u16*)(ws + o);  o = WS_HDR;
    float* Ep       = (float*)(ws + o); o = align256(o + copy_elems * sizeof(float));
    u32*   offs     = (u32*)(ws + o);  o = align256(o + (size_t)n_nodes * 4);
    u32*   cursor   = (u32*)(ws + o);  o = align256(o + (size_t)n_nodes * 4);  // also hist cnt
    u32*   bsum     = (u32*)(ws + o);  o = align256(o + 512 * 4);
    int2*  sg_perm  = (int2*)(ws + o); o = align256(o + (size_t)n_edges * 8);

    const int NB  = (n_nodes + 255) / 256;          // 391 for 100K (<= 512)
    const int EBK = (n_edges + 255) / 256;
    const int EGB = EBK < 2048 ? EBK : 2048;        // grid-stride cap (G11)
    const int ep_quads = (int)(copy_elems / 4);     // copy_elems % 4 == 0

    // 1) prep: weights + cursor zero + Ep zero (fused memsets)
    prep_all<<<dim3(64, 7), 256, 0, stream>>>(W0, W1, W2, W3, W4,
                                              B0, B1, B2, B3, B4, Wt,
                                              cursor, n_nodes, Ep, ep_quads);

    // 2-5) counting sort of edges by tgt
    hist_kernel <<<EGB, 256, 0, stream>>>(tgt, cursor, n_edges);
    scan1_kernel<<<NB, 256, 0, stream>>>(cursor, offs, bsum, n_nodes);
    scan3_kernel<<<NB, 256, 0, stream>>>(offs, bsum, cursor, n_nodes);
    perm_kernel <<<EGB, 256, 0, stream>>>(src, tgt, cursor, sg_perm, n_edges);

    // 6) edge MLP + segment-reduced scatter
    edge_kernel<<<(n_edges + BLK_E - 1) / BLK_E, NTHR, 0, stream>>>(
        t, x, Ofx, sg_perm, Wt, Ep, n_edges);

    // 7) node MLP
    node_kernel<<<(n_nodes + 63) / 64, 256, 0, stream>>>(
        Ep, OW0, OB0, OW1, OB1, (float*)d_out, n_nodes);
}

// Round 16
// 806.627 us; speedup vs baseline: 1.0556x; 1.0556x over previous
//
#include <hip/hip_runtime.h>
#include <hip/hip_bf16.h>

typedef unsigned short u16;
typedef unsigned int u32;
typedef __attribute__((ext_vector_type(8))) short short8;
typedef __attribute__((ext_vector_type(4))) float f32x4;

constexpr int SA     = 160;    // act row stride (bf16): 320 B
constexpr int BLK_E  = 128;    // 4 waves x 32 edges, all waves independent
constexpr int NTHR   = 256;
constexpr int CHUNK  = 512;    // u16 elems per (ks,j) fragment chunk = 1 KB
constexpr int WSLOT  = 50 * CHUNK;              // elems per layer (5 ks x 10 j)
constexpr size_t WS_HDR   = 262144;             // weights header

// slice schedule: s=0 -> (L0,ks0); s=1..15 -> L1..L3 (5 ks each); s=16..20 -> L4
constexpr int Ls (int s) { return s == 0 ? 0 : (s <= 15 ? 1 + (s - 1) / 5 : 4); }
constexpr int Kss(int s) { return s == 0 ? 0 : (s <= 15 ? (s - 1) % 5 : s - 16); }

__device__ __forceinline__ u16 f2bf(float f) {  // RNE (prep only)
    union { float f; unsigned u; } c; c.f = f;
    return (u16)((c.u + 0x7fffu + ((c.u >> 16) & 1u)) >> 16);
}
__device__ __forceinline__ unsigned pk_bf16(float a, float b) {  // v_cvt_pk_bf16_f32
    float2 f; f.x = a; f.y = b;
    __hip_bfloat162 h = __float22bfloat162_rn(f);
    return *(unsigned*)&h;
}

// act k'-storage permutation (tiles 0-3 / 4 / 5-8 / 9)
__device__ __forceinline__ int kperm(int kp) {
    if (kp < 64)  return (kp & 3) * 16 + (kp >> 2);
    if (kp < 128) { const int m = kp - 64; return (5 + (m & 3)) * 16 + (m >> 2); }
    if (kp < 144) return 4 * 16 + (kp - 128);
    if (kp < 160) return 9 * 16 + (kp - 144);
    return 1 << 30;
}

// ---- prep: weights -> fragment chunks + BOTH zero-fills (fused memsets) ----
// blockIdx.y: 0-4 weights, 5 cursor zero, 6 Ep zero (float4).
__global__ void prep_all(const float* __restrict__ W0, const float* __restrict__ W1,
                         const float* __restrict__ W2, const float* __restrict__ W3,
                         const float* __restrict__ W4,
                         const float* __restrict__ B0, const float* __restrict__ B1,
                         const float* __restrict__ B2, const float* __restrict__ B3,
                         const float* __restrict__ B4,
                         u16* __restrict__ Wt, u32* __restrict__ cursor, int n_nodes,
                         float* __restrict__ Ep, int ep_quads)
{
    const int l = blockIdx.y;
    const int tid0 = blockIdx.x * blockDim.x + threadIdx.x;
    const int stride = gridDim.x * blockDim.x;
    if (l == 5) {
        for (int idx = tid0; idx < n_nodes; idx += stride) cursor[idx] = 0u;
        return;
    }
    if (l == 6) {
        float4* p = (float4*)Ep;
        const float4 z4 = {0.f, 0.f, 0.f, 0.f};
        for (int idx = tid0; idx < ep_quads; idx += stride) p[idx] = z4;
        return;
    }
    const float* W; const float* B; int DI, DO; bool perm;
    if      (l == 0) { W = W0; B = B0; DI = 13;  DO = 150; perm = false; }
    else if (l == 1) { W = W1; B = B1; DI = 150; DO = 150; perm = true;  }
    else if (l == 2) { W = W2; B = B2; DI = 150; DO = 150; perm = true;  }
    else if (l == 3) { W = W3; B = B3; DI = 150; DO = 150; perm = true;  }
    else             { W = W4; B = B4; DI = 150; DO = 50;  perm = true;  }
    const int kbias = (l == 0) ? 13 : 150;      // constant-1 input row
    u16* dst = Wt + (size_t)l * WSLOT;
    for (int idx = tid0; idx < WSLOT; idx += stride) {
        const int chunk = idx / CHUNK;            // = ks*10 + j
        const int within = idx - chunk * CHUNK;
        const int lane = within >> 3, e = within & 7;
        const int ks = chunk / 10, j = chunk - ks * 10;
        const int c = lane & 15, q = lane >> 4;
        const int n = j * 16 + c;
        const int kphys = ks * 32 + q * 8 + e;
        const int klog = perm ? kperm(kphys) : kphys;
        float v = 0.f;
        if (n < DO) {
            if (klog < DI)          v = W[klog * DO + n];
            else if (klog == kbias) v = B[n];     // folded bias row
        }
        dst[idx] = f2bf(v);
    }
}

// ---- B half-slice load by half-index h (0..36) -> registers ----------------
__device__ __forceinline__ void loadHalfH(const u16* __restrict__ Wt, int h,
                                          int lane, short8* buf)
{
    int l, ks, g, nch;
    if (h < 32) { const int s = h >> 1; l = Ls(s); ks = Kss(s); g = h & 1; nch = 5; }
    else        { l = 4; ks = h - 32; g = 0; nch = 4; }
    const u16* base = Wt + (size_t)l * WSLOT + (size_t)(ks * 10 + g * 5) * CHUNK
                         + lane * 8;
#pragma unroll
    for (int jj = 0; jj < 5; ++jj)
        if (jj < nch) buf[jj] = *(const short8*)&base[jj * CHUNK];
}

// ---- full-width epilogue: relu + packed bf16, k'-permuted store ------------
__device__ __forceinline__ void epilogueF(u16* act, int ebase, int col, int quad,
                                          f32x4 (&acc)[2][10])
{
#pragma unroll
    for (int mtl = 0; mtl < 2; ++mtl)
#pragma unroll
        for (int r = 0; r < 4; ++r) {
            const int row = ebase + mtl * 16 + quad * 4 + r;
            u16* rp = &act[row * SA];
            uint2 p0, p1;
            p0.x = pk_bf16(fmaxf(acc[mtl][0][r], 0.f), fmaxf(acc[mtl][1][r], 0.f));
            p0.y = pk_bf16(fmaxf(acc[mtl][2][r], 0.f), fmaxf(acc[mtl][3][r], 0.f));
            p1.x = pk_bf16(fmaxf(acc[mtl][5][r], 0.f), fmaxf(acc[mtl][6][r], 0.f));
            p1.y = pk_bf16(fmaxf(acc[mtl][7][r], 0.f), fmaxf(acc[mtl][8][r], 0.f));
            *(uint2*)&rp[col * 4]      = p0;               // tiles 0-3
            *(uint2*)&rp[64 + col * 4] = p1;               // tiles 5-8
            rp[128 + col] = (u16)pk_bf16(fmaxf(acc[mtl][4][r], 0.f), 0.f); // tile 4
            u16 sv = (u16)pk_bf16(fmaxf(acc[mtl][9][r], 0.f), 0.f);
            if (col == 6) sv = 0x3F80;                     // n=150 := 1.0 (bias)
            rp[144 + col] = sv;                            // tile 9
        }
}

// ====================== counting sort of edges by tgt =======================
__global__ void hist_kernel(const int* __restrict__ tgt, u32* __restrict__ cnt,
                            int n_edges)
{
    const int stride = gridDim.x * blockDim.x;
    for (int e = blockIdx.x * blockDim.x + threadIdx.x; e < n_edges; e += stride)
        atomicAdd(&cnt[tgt[e]], 1u);
}

__global__ void scan1_kernel(const u32* __restrict__ cnt, u32* __restrict__ offs,
                             u32* __restrict__ bsum, int n)
{
    __shared__ u32 s[256];
    const int i = blockIdx.x * 256 + threadIdx.x;
    const u32 v = (i < n) ? cnt[i] : 0u;
    s[threadIdx.x] = v; __syncthreads();
#pragma unroll
    for (int d = 1; d < 256; d <<= 1) {
        const u32 t = (threadIdx.x >= d) ? s[threadIdx.x - d] : 0u;
        __syncthreads();
        s[threadIdx.x] += t;
        __syncthreads();
    }
    if (i < n) offs[i] = s[threadIdx.x] - v;         // exclusive within block
    if (threadIdx.x == 255) bsum[blockIdx.x] = s[255];   // RAW block total
}

// scan3 absorbs scan2: each block sums bsum[0..blockIdx) itself.
__global__ void scan3_kernel(const u32* __restrict__ offs, const u32* __restrict__ bsum,
                             u32* __restrict__ cursor, int n)
{
    __shared__ u32 s[256];
    u32 part = 0;
    for (int j = threadIdx.x; j < blockIdx.x; j += 256) part += bsum[j];
    s[threadIdx.x] = part;
    __syncthreads();
#pragma unroll
    for (int d = 128; d > 0; d >>= 1) {
        if (threadIdx.x < d) s[threadIdx.x] += s[threadIdx.x + d];
        __syncthreads();
    }
    const u32 base = s[0];
    const int i = blockIdx.x * 256 + threadIdx.x;
    if (i < n) cursor[i] = offs[i] + base;
}

// perm: single int2 scatter per edge (the PROVEN gather format)
__global__ void perm_kernel(const int* __restrict__ src, const int* __restrict__ tgt,
                            u32* __restrict__ cursor, int2* __restrict__ sg,
                            int n_edges)
{
    const int stride = gridDim.x * blockDim.x;
    for (int e = blockIdx.x * blockDim.x + threadIdx.x; e < n_edges; e += stride) {
        const int g = tgt[e];
        const u32 pos = atomicAdd(&cursor[g], 1u);
        sg[pos] = make_int2(src[e], g);
    }
}

// ------------------------------- Edge kernel --------------------------------
// BARRIER-FREE, wave-owns-32-edges + XCD swizzle + T5 setprio around MFMA
// clusters (R14 placement: prio opens AFTER A-reads — R15 A/B showed opening
// before the ds_reads costs 1%). Best measured: 459 us.
__global__ __launch_bounds__(NTHR, 3) void edge_kernel(
    const float* __restrict__ t, const float* __restrict__ x, const float* __restrict__ Ofx,
    const int2* __restrict__ sgp,
    const u16* __restrict__ Wt,
    float* __restrict__ Ep, int n_edges)
{
    __shared__ __align__(16) u16 act[BLK_E * SA];      // 40960 B exactly

    // bijective XCD-chunk swizzle (m204)
    const int nwg  = gridDim.x;
    const int orig = blockIdx.x;
    const int xcd  = orig & 7;
    const int q = nwg >> 3, r = nwg & 7;
    const int bid = (xcd < r ? xcd * (q + 1) : r * (q + 1) + (xcd - r) * q)
                    + (orig >> 3);

    const int tid   = threadIdx.x;
    const int lane  = tid & 63;
    const int wv    = tid >> 6;        // 0..3
    const int ebase = wv * 32;         // this wave's 32 act rows
    const int col   = lane & 15;
    const int quad  = lane >> 4;

    // ---- gather R': this wave's 32 edges (lanes 0-31, one edge each) -------
    int gval = -1;                     // tgt of this lane's edge (lanes 0-31)
    if (lane < 32) {
        const int e = ebase + lane;
        const long long ge = (long long)bid * BLK_E + e;
        const bool valid = ge < n_edges;
        const int2 sg = valid ? sgp[ge] : make_int2(0, 0);
        gval = valid ? sg.y : -1;
        const float4 xs = valid ? *(const float4*)&x[(size_t)sg.x * 4] : float4{0, 0, 0, 0};
        const float2 os = valid ? *(const float2*)&Ofx[(size_t)sg.x * 2] : float2{0, 0};
        const float4 xg = valid ? *(const float4*)&x[(size_t)sg.y * 4] : float4{0, 0, 0, 0};
        const float2 og = valid ? *(const float2*)&Ofx[(size_t)sg.y * 2] : float2{0, 0};
        const float tv = valid ? t[0] : 0.f;
        uint4 w0, w1;
        w0.x = pk_bf16(xs.x, xs.y); w0.y = pk_bf16(xs.z, xs.w);
        w0.z = pk_bf16(os.x, os.y); w0.w = pk_bf16(xg.x, xg.y);
        w1.x = pk_bf16(xg.z, xg.w); w1.y = pk_bf16(og.x, og.y);
        w1.z = pk_bf16(tv, 1.0f);   w1.w = 0u;     // k=13 := 1 (bias neuron)
        u16* rp = &act[e * SA];
        *(uint4*)&rp[0]  = w0;
        *(uint4*)&rp[8]  = w1;
        *(uint4*)&rp[16] = uint4{0, 0, 0, 0};
        *(uint4*)&rp[24] = uint4{0, 0, 0, 0};
    }
    // no __syncthreads: same-wave DS ordering; rows are wave-private.

    const f32x4 z = {0.f, 0.f, 0.f, 0.f};
    f32x4 acc[2][10];
    short8 Wb[2][5];
    short8 Af[2];

    // prologue: prefetch halves 0 (->Wb[0]) and 1 (->Wb[1])
    loadHalfH(Wt, 0, lane, Wb[0]);
    loadHalfH(Wt, 1, lane, Wb[1]);

    // ---- s=0..15: L0..L3, full N width per wave ----------------------------
#pragma unroll
    for (int s = 0; s <= 15; ++s) {
        const int ks = Kss(s);
        const bool first = (s == 0) || (ks == 0);
#pragma unroll
        for (int mtl = 0; mtl < 2; ++mtl)
            Af[mtl] = *(const short8*)&act[(ebase + mtl * 16 + col) * SA
                                           + ks * 32 + quad * 8];
        __builtin_amdgcn_s_setprio(1);                    // T5: favor MFMA wave
#pragma unroll
        for (int jj = 0; jj < 5; ++jj)
#pragma unroll
            for (int mtl = 0; mtl < 2; ++mtl)
                acc[mtl][jj] = __builtin_amdgcn_mfma_f32_16x16x32_bf16(
                    Af[mtl], Wb[0][jj], first ? z : acc[mtl][jj], 0, 0, 0);
        __builtin_amdgcn_s_setprio(0);
        loadHalfH(Wt, 2 * s + 2, lane, Wb[0]);            // <= 32
        __builtin_amdgcn_s_setprio(1);
#pragma unroll
        for (int jj = 0; jj < 5; ++jj)
#pragma unroll
            for (int mtl = 0; mtl < 2; ++mtl)
                acc[mtl][5 + jj] = __builtin_amdgcn_mfma_f32_16x16x32_bf16(
                    Af[mtl], Wb[1][jj], first ? z : acc[mtl][5 + jj], 0, 0, 0);
        __builtin_amdgcn_s_setprio(0);
        loadHalfH(Wt, 2 * s + 3, lane, Wb[1]);            // <= 33
        if (s == 0 || ks == 4)
            epilogueF(act, ebase, col, quad, acc);
    }

    // ---- L4: ks=0..4, N=50 (4 tiles), both M-tiles -------------------------
    f32x4 acc4[2][4];
#pragma unroll
    for (int ks4 = 0; ks4 < 5; ++ks4) {
        const int h = 32 + ks4;
#pragma unroll
        for (int mtl = 0; mtl < 2; ++mtl)
            Af[mtl] = *(const short8*)&act[(ebase + mtl * 16 + col) * SA
                                           + ks4 * 32 + quad * 8];
        __builtin_amdgcn_s_setprio(1);
#pragma unroll
        for (int jj = 0; jj < 4; ++jj)
#pragma unroll
            for (int mtl = 0; mtl < 2; ++mtl)
                acc4[mtl][jj] = __builtin_amdgcn_mfma_f32_16x16x32_bf16(
                    Af[mtl], Wb[h & 1][jj], (ks4 == 0) ? z : acc4[mtl][jj], 0, 0, 0);
        __builtin_amdgcn_s_setprio(0);
        if (h + 2 <= 36) loadHalfH(Wt, h + 2, lane, Wb[h & 1]);
    }

    // ---- wave-private E tile + run-scan scatter ----------------------------
    float* actF = (float*)&act[ebase * SA];   // f32 [32][52] on own rows
#pragma unroll
    for (int mtl = 0; mtl < 2; ++mtl)
#pragma unroll
        for (int jj = 0; jj < 4; ++jj) {
            const int n = jj * 16 + col;
            if (n < 50) {
#pragma unroll
                for (int r = 0; r < 4; ++r)
                    actF[(mtl * 16 + quad * 4 + r) * 52 + n] = acc4[mtl][jj][r];
            }
        }
    if (lane < 50) {
        const int c = lane;
        int   cur = __shfl(gval, 0);
        float a   = 0.f;
#pragma unroll
        for (int rb = 0; rb < 4; ++rb) {
            float vb[8];
#pragma unroll
            for (int j = 0; j < 8; ++j)
                vb[j] = actF[(rb * 8 + j) * 52 + c];
#pragma unroll
            for (int j = 0; j < 8; ++j) {
                const int g = __shfl(gval, rb * 8 + j);
                if (g != cur) {
                    if (cur >= 0) atomicAdd(&Ep[(size_t)cur * 50 + c], a);
                    a = 0.f; cur = g;
                }
                a += vb[j];
            }
        }
        if (cur >= 0) atomicAdd(&Ep[(size_t)cur * 50 + c], a);
    }
}

// ---------------- Node kernel: fO MLP (fp32 VALU) ---------------------------
template<int DI, int DO, bool RELU>
__device__ __forceinline__ void mlp_layer_t(
    const float* __restrict__ W, const float* __restrict__ B,
    float (*in)[64], float (*out)[64], int tid)
{
    const int et = tid & 15;
    const int jt = tid >> 4;
    constexpr int NG = (DO + 15) / 16;

    float acc0[NG], acc1[NG], acc2[NG], acc3[NG];
#pragma unroll
    for (int g = 0; g < NG; ++g) {
        const int j = jt + 16 * g;
        const float bb = (j < DO) ? B[j] : 0.f;
        acc0[g] = bb; acc1[g] = bb; acc2[g] = bb; acc3[g] = bb;
    }
    for (int k = 0; k < DI; ++k) {
        const float4 a = *(const float4*)&in[k][et * 4];
#pragma unroll
        for (int g = 0; g < NG; ++g) {
            const int j = jt + 16 * g;
            const float wv = (j < DO) ? W[k * DO + j] : 0.f;
            acc0[g] = fmaf(a.x, wv, acc0[g]);
            acc1[g] = fmaf(a.y, wv, acc1[g]);
            acc2[g] = fmaf(a.z, wv, acc2[g]);
            acc3[g] = fmaf(a.w, wv, acc3[g]);
        }
    }
#pragma unroll
    for (int g = 0; g < NG; ++g) {
        const int j = jt + 16 * g;
        if (j < DO) {
            float4 v; v.x = acc0[g]; v.y = acc1[g]; v.z = acc2[g]; v.w = acc3[g];
            if (RELU) {
                v.x = fmaxf(v.x, 0.f); v.y = fmaxf(v.y, 0.f);
                v.z = fmaxf(v.z, 0.f); v.w = fmaxf(v.w, 0.f);
            }
            *(float4*)&out[j][et * 4] = v;
        }
    }
}

__global__ __launch_bounds__(256, 3) void node_kernel(
    const float* __restrict__ Ep,
    const float* __restrict__ W0, const float* __restrict__ B0,
    const float* __restrict__ W1, const float* __restrict__ B1,
    float* __restrict__ P, int n_nodes)
{
    __shared__ float bufA[104][64];
    __shared__ float bufB[104][64];
    const int tid = threadIdx.x;
    const int n0  = blockIdx.x * 64;

    for (int idx = tid; idx < 64 * 50; idx += 256) {
        const int e = idx / 50;
        const int k = idx - e * 50;
        const int n = n0 + e;
        bufA[k][e] = (n < n_nodes) ? Ep[(size_t)n * 50 + k] : 0.f;
    }
    __syncthreads();
    mlp_layer_t<50, 100, true >(W0, B0, bufA, bufB, tid); __syncthreads();
    mlp_layer_t<100, 4, false>(W1, B1, bufB, bufA, tid); __syncthreads();
    for (int idx = tid; idx < 64 * 4; idx += 256) {
        const int e = idx & 63;
        const int j = idx >> 6;
        const int n = n0 + e;
        if (n < n_nodes) P[(size_t)n * 4 + j] = bufA[j][e];
    }
}

// ------------------------------- launcher -----------------------------------
extern "C" void kernel_launch(void* const* d_in, const int* in_sizes, int n_in,
                              void* d_out, int out_size, void* d_ws, size_t ws_size,
                              hipStream_t stream)
{
    const float* t   = (const float*)d_in[0];
    const float* x   = (const float*)d_in[1];
    const float* Ofx = (const float*)d_in[2];
    const int*   src = (const int*)d_in[3];
    const int*   tgt = (const int*)d_in[4];
    const float* W0  = (const float*)d_in[5];  const float* B0 = (const float*)d_in[6];
    const float* W1  = (const float*)d_in[7];  const float* B1 = (const float*)d_in[8];
    const float* W2  = (const float*)d_in[9];  const float* B2 = (const float*)d_in[10];
    const float* W3  = (const float*)d_in[11]; const float* B3 = (const float*)d_in[12];
    const float* W4  = (const float*)d_in[13]; const float* B4 = (const float*)d_in[14];
    const float* OW0 = (const float*)d_in[15]; const float* OB0 = (const float*)d_in[16];
    const float* OW1 = (const float*)d_in[17]; const float* OB1 = (const float*)d_in[18];

    const int n_nodes = in_sizes[1] / 4;
    const int n_edges = in_sizes[3];

    // workspace layout (all 256-B aligned)
    auto align256 = [](size_t v) { return (v + 255) & ~(size_t)255; };
    char* ws = (char*)d_ws;
    const size_t copy_elems = (size_t)n_nodes * 50;
    size_t o = 0;
    u16*   Wt       = (u16*)(ws + o);  o = WS_HDR;
    float* Ep       = (float*)(ws + o); o = align256(o + copy_elems * sizeof(float));
    u32*   offs     = (u32*)(ws + o);  o = align256(o + (size_t)n_nodes * 4);
    u32*   cursor   = (u32*)(ws + o);  o = align256(o + (size_t)n_nodes * 4);  // also hist cnt
    u32*   bsum     = (u32*)(ws + o);  o = align256(o + 512 * 4);
    int2*  sg_perm  = (int2*)(ws + o); o = align256(o + (size_t)n_edges * 8);

    const int NB  = (n_nodes + 255) / 256;          // 391 for 100K (<= 512)
    const int EBK = (n_edges + 255) / 256;
    const int EGB = EBK < 2048 ? EBK : 2048;        // grid-stride cap (G11)
    const int ep_quads = (int)(copy_elems / 4);     // copy_elems % 4 == 0

    // 1) prep: weights + cursor zero + Ep zero (fused memsets)
    prep_all<<<dim3(64, 7), 256, 0, stream>>>(W0, W1, W2, W3, W4,
                                              B0, B1, B2, B3, B4, Wt,
                                              cursor, n_nodes, Ep, ep_quads);

    // 2-5) counting sort of edges by tgt
    hist_kernel <<<EGB, 256, 0, stream>>>(tgt, cursor, n_edges);
    scan1_kernel<<<NB, 256, 0, stream>>>(cursor, offs, bsum, n_nodes);
    scan3_kernel<<<NB, 256, 0, stream>>>(offs, bsum, cursor, n_nodes);
    perm_kernel <<<EGB, 256, 0, stream>>>(src, tgt, cursor, sg_perm, n_edges);

    // 6) edge MLP + segment-reduced scatter
    edge_kernel<<<(n_edges + BLK_E - 1) / BLK_E, NTHR, 0, stream>>>(
        t, x, Ofx, sg_perm, Wt, Ep, n_edges);

    // 7) node MLP
    node_kernel<<<(n_nodes + 63) / 64, 256, 0, stream>>>(
        Ep, OW0, OB0, OW1, OB1, (float*)d_out, n_nodes);
}